// Round 2
// baseline (2285.186 us; speedup 1.0000x reference)
//
#include <hip/hip_runtime.h>
#include <hip/hip_bf16.h>

typedef __hip_bfloat16 bf16;

#define SEQ    4096
#define DMODEL 1024
#define NHEAD  16
#define DKH    64   // per-head dim

__device__ __forceinline__ float ldf(const float* p, size_t i) { return p[i]; }
__device__ __forceinline__ float ldf(const bf16*  p, size_t i) { return __bfloat162float(p[i]); }
__device__ __forceinline__ void stf(float* p, size_t i, float v) { p[i] = v; }
__device__ __forceinline__ void stf(bf16*  p, size_t i, float v) { p[i] = __float2bfloat16(v); }

// Decide whether device buffers hold bf16 (flag=1) or fp32 (flag=0).
// Samples x (N(0,1) values): as u16 stream, bf16 storage gives sane bf16
// exponent fields nearly everywhere; fp32 storage gives random bits in the
// low halves (~10% sane). 512 samples: bf16 ~508 sane, fp32 ~282 sane.
__global__ void detect_dtype(const unsigned short* __restrict__ x, int* __restrict__ flag) {
    int lane = threadIdx.x;
    int cnt = 0;
    for (int i = lane; i < 512; i += 64) {
        int e = (x[i] >> 7) & 0xFF;
        cnt += (e >= 100 && e <= 140) ? 1 : 0;
    }
    #pragma unroll
    for (int off = 32; off; off >>= 1) cnt += __shfl_xor(cnt, off, 64);
    if (lane == 0) *flag = (cnt >= 400) ? 1 : 0;
}

// C[m,n] = sum_k A[m,k] * B[n,k] + bias[n]
// A: MxK row-major, B: NxK row-major, C: MxN row-major. M,N mult of 64, K mult of 32.
template <typename TA, typename TB, typename TC>
__device__ void gemm_body(const TA* __restrict__ A, const TB* __restrict__ B,
                          const TB* __restrict__ bias, TC* __restrict__ C,
                          int M, int N, int K, float As[][33], float Bs[][33]) {
    const int tid = threadIdx.x;
    const int tx = tid & 15, ty = tid >> 4;
    const int m0 = blockIdx.x * 64, n0 = blockIdx.y * 64;

    float acc[4][4] = {};

    for (int k0 = 0; k0 < K; k0 += 32) {
        #pragma unroll
        for (int i = 0; i < 8; ++i) {
            int idx = tid + i * 256;
            int r = idx >> 5, c = idx & 31;
            As[r][c] = ldf(A, (size_t)(m0 + r) * K + k0 + c);
            Bs[r][c] = ldf(B, (size_t)(n0 + r) * K + k0 + c);
        }
        __syncthreads();
        #pragma unroll 8
        for (int kk = 0; kk < 32; ++kk) {
            float a[4], b[4];
            #pragma unroll
            for (int i = 0; i < 4; ++i) a[i] = As[ty * 4 + i][kk];
            #pragma unroll
            for (int j = 0; j < 4; ++j) b[j] = Bs[tx * 4 + j][kk];
            #pragma unroll
            for (int i = 0; i < 4; ++i)
                #pragma unroll
                for (int j = 0; j < 4; ++j)
                    acc[i][j] = fmaf(a[i], b[j], acc[i][j]);
        }
        __syncthreads();
    }

    #pragma unroll
    for (int i = 0; i < 4; ++i) {
        int m = m0 + ty * 4 + i;
        #pragma unroll
        for (int j = 0; j < 4; ++j) {
            int n = n0 + tx * 4 + j;
            stf(C, (size_t)m * N + n, acc[i][j] + ldf(bias, (size_t)n));
        }
    }
}

// Projections: A/B/bias in data dtype, C = bf16 intermediate.
__global__ __launch_bounds__(256)
void gemm_proj(const void* __restrict__ A, const void* __restrict__ B,
               const void* __restrict__ bias, bf16* __restrict__ C,
               const int* __restrict__ flag, int M, int N, int K) {
    __shared__ float As[64][33];
    __shared__ float Bs[64][33];
    if (*flag)
        gemm_body<bf16, bf16, bf16>((const bf16*)A, (const bf16*)B, (const bf16*)bias, C, M, N, K, As, Bs);
    else
        gemm_body<float, float, bf16>((const float*)A, (const float*)B, (const float*)bias, C, M, N, K, As, Bs);
}

// Output projection: A = bf16 intermediate, B/bias/C in data dtype.
__global__ __launch_bounds__(256)
void gemm_out(const bf16* __restrict__ A, const void* __restrict__ B,
              const void* __restrict__ bias, void* __restrict__ C,
              const int* __restrict__ flag, int M, int N, int K) {
    __shared__ float As[64][33];
    __shared__ float Bs[64][33];
    if (*flag)
        gemm_body<bf16, bf16, bf16>(A, (const bf16*)B, (const bf16*)bias, (bf16*)C, M, N, K, As, Bs);
    else
        gemm_body<bf16, float, float>(A, (const float*)B, (const float*)bias, (float*)C, M, N, K, As, Bs);
}

// One block per (64-row q tile, head). Online softmax, never materializes SxS.
template <typename TS>
__device__ void flash_body(const bf16* __restrict__ Q, const bf16* __restrict__ Kg,
                           const bf16* __restrict__ Vg, const TS* __restrict__ sim,
                           bf16* __restrict__ O,
                           float Qs[][65], float KVs[][65], float Ps[][65]) {
    const int tid = threadIdx.x;
    const int tx = tid & 15, ty = tid >> 4;
    const int q0 = blockIdx.x * 64;
    const int hd = blockIdx.y * DKH;

    #pragma unroll
    for (int i = 0; i < 16; ++i) {
        int idx = tid + i * 256;
        int r = idx >> 6, c = idx & 63;
        Qs[r][c] = ldf(Q, (size_t)(q0 + r) * DMODEL + hd + c) * 0.125f;
    }

    float acc[4][4] = {};
    float Mrow[4], Lrow[4];
    #pragma unroll
    for (int i = 0; i < 4; ++i) { Mrow[i] = -1e30f; Lrow[i] = 0.f; }
    __syncthreads();

    for (int t = 0; t < SEQ / 64; ++t) {
        const int k0 = t * 64;
        #pragma unroll
        for (int i = 0; i < 16; ++i) {
            int idx = tid + i * 256;
            int r = idx >> 6, c = idx & 63;
            KVs[r][c] = ldf(Kg, (size_t)(k0 + r) * DMODEL + hd + c);
        }
        __syncthreads();

        float s[4][4] = {};
        for (int kk = 0; kk < 64; ++kk) {
            float a[4], bb[4];
            #pragma unroll
            for (int i = 0; i < 4; ++i) a[i] = Qs[ty * 4 + i][kk];
            #pragma unroll
            for (int j = 0; j < 4; ++j) bb[j] = KVs[tx * 4 + j][kk];
            #pragma unroll
            for (int i = 0; i < 4; ++i)
                #pragma unroll
                for (int j = 0; j < 4; ++j)
                    s[i][j] = fmaf(a[i], bb[j], s[i][j]);
        }
        #pragma unroll
        for (int i = 0; i < 4; ++i)
            #pragma unroll
            for (int j = 0; j < 4; ++j)
                s[i][j] += ldf(sim, (size_t)(q0 + ty * 4 + i) * SEQ + k0 + tx * 4 + j);

        float rm[4];
        #pragma unroll
        for (int i = 0; i < 4; ++i)
            rm[i] = fmaxf(fmaxf(s[i][0], s[i][1]), fmaxf(s[i][2], s[i][3]));
        #pragma unroll
        for (int off = 1; off < 16; off <<= 1)
            #pragma unroll
            for (int i = 0; i < 4; ++i)
                rm[i] = fmaxf(rm[i], __shfl_xor(rm[i], off, 64));

        float alpha[4], rsum[4];
        #pragma unroll
        for (int i = 0; i < 4; ++i) {
            float mn = fmaxf(Mrow[i], rm[i]);
            alpha[i] = __expf(Mrow[i] - mn);
            Mrow[i] = mn;
            rsum[i] = 0.f;
        }
        #pragma unroll
        for (int i = 0; i < 4; ++i)
            #pragma unroll
            for (int j = 0; j < 4; ++j) {
                s[i][j] = __expf(s[i][j] - Mrow[i]);
                rsum[i] += s[i][j];
            }
        #pragma unroll
        for (int off = 1; off < 16; off <<= 1)
            #pragma unroll
            for (int i = 0; i < 4; ++i)
                rsum[i] += __shfl_xor(rsum[i], off, 64);
        #pragma unroll
        for (int i = 0; i < 4; ++i)
            Lrow[i] = Lrow[i] * alpha[i] + rsum[i];

        __syncthreads();  // everyone done reading K from KVs

        #pragma unroll
        for (int i = 0; i < 4; ++i)
            #pragma unroll
            for (int j = 0; j < 4; ++j)
                Ps[ty * 4 + i][tx * 4 + j] = s[i][j];
        #pragma unroll
        for (int i = 0; i < 16; ++i) {
            int idx = tid + i * 256;
            int r = idx >> 6, c = idx & 63;
            KVs[r][c] = ldf(Vg, (size_t)(k0 + r) * DMODEL + hd + c);
        }
        __syncthreads();

        #pragma unroll
        for (int i = 0; i < 4; ++i)
            #pragma unroll
            for (int j = 0; j < 4; ++j)
                acc[i][j] *= alpha[i];
        for (int kk = 0; kk < 64; ++kk) {
            float p[4], vv[4];
            #pragma unroll
            for (int i = 0; i < 4; ++i) p[i] = Ps[ty * 4 + i][kk];
            #pragma unroll
            for (int j = 0; j < 4; ++j) vv[j] = KVs[kk][tx * 4 + j];
            #pragma unroll
            for (int i = 0; i < 4; ++i)
                #pragma unroll
                for (int j = 0; j < 4; ++j)
                    acc[i][j] = fmaf(p[i], vv[j], acc[i][j]);
        }
        __syncthreads();  // done with Ps / V before next iter overwrites
    }

    #pragma unroll
    for (int i = 0; i < 4; ++i) {
        float inv = 1.f / Lrow[i];
        #pragma unroll
        for (int j = 0; j < 4; ++j)
            O[(size_t)(q0 + ty * 4 + i) * DMODEL + hd + tx * 4 + j] =
                __float2bfloat16(acc[i][j] * inv);
    }
}

__global__ __launch_bounds__(256)
void flash_dual(const bf16* __restrict__ Q, const bf16* __restrict__ K,
                const bf16* __restrict__ V, const void* __restrict__ sim,
                bf16* __restrict__ O, const int* __restrict__ flag) {
    __shared__ float Qs[64][65];
    __shared__ float KVs[64][65];
    __shared__ float Ps[64][65];
    if (*flag)
        flash_body<bf16>(Q, K, V, (const bf16*)sim, O, Qs, KVs, Ps);
    else
        flash_body<float>(Q, K, V, (const float*)sim, O, Qs, KVs, Ps);
}

extern "C" void kernel_launch(void* const* d_in, const int* in_sizes, int n_in,
                              void* d_out, int out_size, void* d_ws, size_t ws_size,
                              hipStream_t stream) {
    int* flagw = (int*)d_ws;
    const int* flag = (const int*)d_ws;
    bf16* Q = (bf16*)((char*)d_ws + 256);
    bf16* K = Q + (size_t)SEQ * DMODEL;
    bf16* V = K + (size_t)SEQ * DMODEL;
    bf16* O = V + (size_t)SEQ * DMODEL;

    detect_dtype<<<1, 64, 0, stream>>>((const unsigned short*)d_in[0], flagw);

    dim3 gp(SEQ / 64, DMODEL / 64);
    dim3 blk(256);
    gemm_proj<<<gp, blk, 0, stream>>>(d_in[0], d_in[2], d_in[3], Q, flag, SEQ, DMODEL, DMODEL);
    gemm_proj<<<gp, blk, 0, stream>>>(d_in[0], d_in[4], d_in[5], K, flag, SEQ, DMODEL, DMODEL);
    gemm_proj<<<gp, blk, 0, stream>>>(d_in[0], d_in[6], d_in[7], V, flag, SEQ, DMODEL, DMODEL);

    flash_dual<<<dim3(SEQ / 64, NHEAD), blk, 0, stream>>>(Q, K, V, d_in[1], O, flag);

    gemm_out<<<gp, blk, 0, stream>>>(O, d_in[8], d_in[9], d_out, flag, SEQ, DMODEL, DMODEL);
}

// Round 3
// 615.322 us; speedup vs baseline: 3.7138x; 3.7138x over previous
//
#include <hip/hip_runtime.h>
#include <hip/hip_bf16.h>

typedef __hip_bfloat16 bf16;
typedef __attribute__((ext_vector_type(8))) short short8;
typedef __attribute__((ext_vector_type(4))) float f32x4;

#define SEQ    4096
#define DMODEL 1024
#define NHEAD  16
#define DKH    64

#define LSTRIDE 72   // bf16 LDS row stride (144 B = 9*16 -> b128-aligned rows)
#define SSTRIDE 68   // f32 LDS row stride (272 B = 17*16)
#define GSTRIDE 40   // bf16 LDS row stride for 32-wide GEMM tiles (80 B = 5*16)

__device__ __forceinline__ float ldf(const float* p, size_t i) { return p[i]; }
__device__ __forceinline__ float ldf(const bf16*  p, size_t i) { return __bfloat162float(p[i]); }
__device__ __forceinline__ void stf(float* p, size_t i, float v) { p[i] = v; }
__device__ __forceinline__ void stf(bf16*  p, size_t i, float v) { p[i] = __float2bfloat16(v); }

__device__ __forceinline__ short f2bs(float v) {
    bf16 b = __float2bfloat16(v);
    return *(short*)&b;
}
__device__ __forceinline__ float bs2f(short s) {
    bf16 b; *(short*)&b = s;
    return __bfloat162float(b);
}

// load 8 contiguous elems as bf16 bit pattern
__device__ __forceinline__ short8 lda8(const bf16* p, size_t i) {
    return *(const short8*)(p + i);
}
__device__ __forceinline__ short8 lda8(const float* p, size_t i) {
    float4 a = *(const float4*)(p + i);
    float4 b = *(const float4*)(p + i + 4);
    short8 r;
    r[0] = f2bs(a.x); r[1] = f2bs(a.y); r[2] = f2bs(a.z); r[3] = f2bs(a.w);
    r[4] = f2bs(b.x); r[5] = f2bs(b.y); r[6] = f2bs(b.z); r[7] = f2bs(b.w);
    return r;
}

// bf16 (flag=1) vs fp32 (flag=0) storage detector (unchanged from round 2 — it worked).
__global__ void detect_dtype(const unsigned short* __restrict__ x, int* __restrict__ flag) {
    int lane = threadIdx.x;
    int cnt = 0;
    for (int i = lane; i < 512; i += 64) {
        int e = (x[i] >> 7) & 0xFF;
        cnt += (e >= 100 && e <= 140) ? 1 : 0;
    }
    #pragma unroll
    for (int off = 32; off; off >>= 1) cnt += __shfl_xor(cnt, off, 64);
    if (lane == 0) *flag = (cnt >= 400) ? 1 : 0;
}

// ---------------- MFMA GEMM: C[m,n] = sum_k A[m,k]*B[n,k] + bias[n] ----------------
// 128x128 tile, BK=32, 256 threads = 4 waves, each wave a 64x64 quadrant (4x4 frags).
template <typename TA, typename TB, typename TC>
__device__ void gemm_mfma_body(const TA* __restrict__ A, const TB* __restrict__ B,
                               const TB* __restrict__ bias, TC* __restrict__ C,
                               int M, int N, int K, short* As, short* Bs) {
    const int tid = threadIdx.x;
    const int w = tid >> 6, lane = tid & 63, q = lane >> 4, c = lane & 15;
    const int m0 = blockIdx.x * 128, n0 = blockIdx.y * 128;
    const int mb = 64 * (w & 1), nb = 64 * (w >> 1);

    f32x4 acc[4][4] = {};

    for (int k0 = 0; k0 < K; k0 += 32) {
        __syncthreads();
        #pragma unroll
        for (int i = 0; i < 2; ++i) {
            int ch = tid + 256 * i;
            int r = ch >> 2, c8 = (ch & 3) * 8;
            *(short8*)&As[r * GSTRIDE + c8] = lda8(A, (size_t)(m0 + r) * K + k0 + c8);
            *(short8*)&Bs[r * GSTRIDE + c8] = lda8(B, (size_t)(n0 + r) * K + k0 + c8);
        }
        __syncthreads();
        short8 af[4], bfr[4];
        #pragma unroll
        for (int i = 0; i < 4; ++i)
            af[i] = *(const short8*)&As[(mb + i * 16 + c) * GSTRIDE + q * 8];
        #pragma unroll
        for (int j = 0; j < 4; ++j)
            bfr[j] = *(const short8*)&Bs[(nb + j * 16 + c) * GSTRIDE + q * 8];
        #pragma unroll
        for (int i = 0; i < 4; ++i)
            #pragma unroll
            for (int j = 0; j < 4; ++j)
                acc[i][j] = __builtin_amdgcn_mfma_f32_16x16x32_bf16(af[i], bfr[j], acc[i][j], 0, 0, 0);
    }

    #pragma unroll
    for (int j = 0; j < 4; ++j) {
        int n = n0 + nb + j * 16 + c;
        float bj = ldf(bias, (size_t)n);
        #pragma unroll
        for (int i = 0; i < 4; ++i)
            #pragma unroll
            for (int t = 0; t < 4; ++t) {
                int m = m0 + mb + i * 16 + q * 4 + t;
                stf(C, (size_t)m * N + n, acc[i][j][t] + bj);
            }
    }
}

__global__ __launch_bounds__(256)
void gemm_proj_mfma(const void* __restrict__ A, const void* __restrict__ B,
                    const void* __restrict__ bias, bf16* __restrict__ C,
                    const int* __restrict__ flag, int M, int N, int K) {
    __shared__ __align__(16) short As[128 * GSTRIDE];
    __shared__ __align__(16) short Bs[128 * GSTRIDE];
    if (*flag)
        gemm_mfma_body<bf16, bf16, bf16>((const bf16*)A, (const bf16*)B, (const bf16*)bias, C, M, N, K, As, Bs);
    else
        gemm_mfma_body<float, float, bf16>((const float*)A, (const float*)B, (const float*)bias, C, M, N, K, As, Bs);
}

__global__ __launch_bounds__(256)
void gemm_out_mfma(const bf16* __restrict__ A, const void* __restrict__ B,
                   const void* __restrict__ bias, void* __restrict__ C,
                   const int* __restrict__ flag, int M, int N, int K) {
    __shared__ __align__(16) short As[128 * GSTRIDE];
    __shared__ __align__(16) short Bs[128 * GSTRIDE];
    if (*flag)
        gemm_mfma_body<bf16, bf16, bf16>(A, (const bf16*)B, (const bf16*)bias, (bf16*)C, M, N, K, As, Bs);
    else
        gemm_mfma_body<bf16, float, float>(A, (const float*)B, (const float*)bias, (float*)C, M, N, K, As, Bs);
}

// ---------------- MFMA flash attention ----------------
// Block = 256 threads (4 waves), 64 Q rows x one head. Wave w owns rows 16w..16w+15.
__global__ __launch_bounds__(256)
void flash_mfma(const bf16* __restrict__ Q, const bf16* __restrict__ Kg,
                const bf16* __restrict__ Vg, const void* __restrict__ simv,
                bf16* __restrict__ O, const int* __restrict__ flag) {
    __shared__ __align__(16) short Qs[64 * LSTRIDE];
    __shared__ __align__(16) short Ks[64 * LSTRIDE];
    __shared__ __align__(16) short Vt[64 * LSTRIDE];  // V transposed: Vt[d][n]
    __shared__ __align__(16) short Ps[64 * LSTRIDE];
    __shared__ __align__(16) float Ss[64 * SSTRIDE];  // sim tile, fp32

    const int tid = threadIdx.x;
    const int w = tid >> 6, lane = tid & 63, q = lane >> 4, c = lane & 15;
    const int q0 = blockIdx.x * 64, hd = blockIdx.y * DKH;
    const bool isbf = (*flag != 0);
    const bf16* simb = (const bf16*)simv;
    const float* simf = (const float*)simv;

    // stage Q tile (unscaled; 1/8 applied post-MFMA)
    #pragma unroll
    for (int i = 0; i < 2; ++i) {
        int ch = tid + 256 * i;
        int r = ch >> 3, c8 = (ch & 7) * 8;
        *(short8*)&Qs[r * LSTRIDE + c8] = *(const short8*)&Q[(size_t)(q0 + r) * DMODEL + hd + c8];
    }

    f32x4 accO[4] = {};
    float Mrow[4], Lrow[4];
    #pragma unroll
    for (int i = 0; i < 4; ++i) { Mrow[i] = -1e30f; Lrow[i] = 0.f; }

    for (int t = 0; t < SEQ / 64; ++t) {
        const int k0 = t * 64;
        __syncthreads();  // prior iter's LDS reads complete

        // stage K tile
        #pragma unroll
        for (int i = 0; i < 2; ++i) {
            int ch = tid + 256 * i;
            int r = ch >> 3, c8 = (ch & 7) * 8;
            *(short8*)&Ks[r * LSTRIDE + c8] = *(const short8*)&Kg[(size_t)(k0 + r) * DMODEL + hd + c8];
        }
        // stage V transposed: thread gathers column d over 8 n's (coalesced across lanes)
        #pragma unroll
        for (int i = 0; i < 2; ++i) {
            int d = tid & 63, n0 = ((tid >> 6) + 4 * i) * 8;
            short8 vv;
            #pragma unroll
            for (int j = 0; j < 8; ++j) {
                bf16 b = Vg[(size_t)(k0 + n0 + j) * DMODEL + hd + d];
                vv[j] = *(short*)&b;
            }
            *(short8*)&Vt[d * LSTRIDE + n0] = vv;
        }
        // stage sim tile -> fp32 LDS
        if (isbf) {
            #pragma unroll
            for (int i = 0; i < 2; ++i) {
                int ch = tid + 256 * i;
                int r = ch >> 3, c8 = (ch & 7) * 8;
                short8 sv8 = *(const short8*)&simb[(size_t)(q0 + r) * SEQ + k0 + c8];
                float4 lo, hi;
                lo.x = bs2f(sv8[0]); lo.y = bs2f(sv8[1]); lo.z = bs2f(sv8[2]); lo.w = bs2f(sv8[3]);
                hi.x = bs2f(sv8[4]); hi.y = bs2f(sv8[5]); hi.z = bs2f(sv8[6]); hi.w = bs2f(sv8[7]);
                *(float4*)&Ss[r * SSTRIDE + c8] = lo;
                *(float4*)&Ss[r * SSTRIDE + c8 + 4] = hi;
            }
        } else {
            #pragma unroll
            for (int i = 0; i < 4; ++i) {
                int ch = tid + 256 * i;
                int r = ch >> 4, c4 = (ch & 15) * 4;
                *(float4*)&Ss[r * SSTRIDE + c4] = *(const float4*)&simf[(size_t)(q0 + r) * SEQ + k0 + c4];
            }
        }
        __syncthreads();  // staging visible

        // QK^T: S strip rows 16w..16w+15, cols 0..63
        short8 aq0 = *(const short8*)&Qs[(16 * w + c) * LSTRIDE + q * 8];
        short8 aq1 = *(const short8*)&Qs[(16 * w + c) * LSTRIDE + 32 + q * 8];
        f32x4 sfr[4];
        #pragma unroll
        for (int f = 0; f < 4; ++f) {
            short8 bk0 = *(const short8*)&Ks[(f * 16 + c) * LSTRIDE + q * 8];
            short8 bk1 = *(const short8*)&Ks[(f * 16 + c) * LSTRIDE + 32 + q * 8];
            f32x4 a = {};
            a = __builtin_amdgcn_mfma_f32_16x16x32_bf16(aq0, bk0, a, 0, 0, 0);
            a = __builtin_amdgcn_mfma_f32_16x16x32_bf16(aq1, bk1, a, 0, 0, 0);
            sfr[f] = a;
        }

        // softmax (rows q*4+i live in the 16 lanes of this quad)
        float sv[4][4], rmax[4];
        #pragma unroll
        for (int i = 0; i < 4; ++i) rmax[i] = -1e30f;
        #pragma unroll
        for (int f = 0; f < 4; ++f)
            #pragma unroll
            for (int i = 0; i < 4; ++i) {
                float s = sfr[f][i] * 0.125f + Ss[(16 * w + q * 4 + i) * SSTRIDE + f * 16 + c];
                sv[f][i] = s;
                rmax[i] = fmaxf(rmax[i], s);
            }
        #pragma unroll
        for (int off = 1; off < 16; off <<= 1)
            #pragma unroll
            for (int i = 0; i < 4; ++i)
                rmax[i] = fmaxf(rmax[i], __shfl_xor(rmax[i], off, 64));

        float alpha[4], rsum[4];
        #pragma unroll
        for (int i = 0; i < 4; ++i) {
            float mn = fmaxf(Mrow[i], rmax[i]);
            alpha[i] = __expf(Mrow[i] - mn);
            Mrow[i] = mn;
            rsum[i] = 0.f;
        }
        #pragma unroll
        for (int f = 0; f < 4; ++f)
            #pragma unroll
            for (int i = 0; i < 4; ++i) {
                float p = __expf(sv[f][i] - Mrow[i]);
                sv[f][i] = p;
                rsum[i] += p;
            }
        #pragma unroll
        for (int off = 1; off < 16; off <<= 1)
            #pragma unroll
            for (int i = 0; i < 4; ++i)
                rsum[i] += __shfl_xor(rsum[i], off, 64);
        #pragma unroll
        for (int i = 0; i < 4; ++i)
            Lrow[i] = Lrow[i] * alpha[i] + rsum[i];

        // write P (bf16) into A-operand layout via LDS
        #pragma unroll
        for (int f = 0; f < 4; ++f)
            #pragma unroll
            for (int i = 0; i < 4; ++i)
                Ps[(16 * w + q * 4 + i) * LSTRIDE + f * 16 + c] = f2bs(sv[f][i]);

        // rescale O accumulator (register-local)
        #pragma unroll
        for (int f = 0; f < 4; ++f)
            #pragma unroll
            for (int i = 0; i < 4; ++i)
                accO[f][i] *= alpha[i];

        __syncthreads();  // Ps visible to all waves

        // PV: O[m][d] += sum_n P[m][n] * Vt[d][n]
        short8 ap0 = *(const short8*)&Ps[(16 * w + c) * LSTRIDE + q * 8];
        short8 ap1 = *(const short8*)&Ps[(16 * w + c) * LSTRIDE + 32 + q * 8];
        #pragma unroll
        for (int f = 0; f < 4; ++f) {
            short8 bv0 = *(const short8*)&Vt[(f * 16 + c) * LSTRIDE + q * 8];
            short8 bv1 = *(const short8*)&Vt[(f * 16 + c) * LSTRIDE + 32 + q * 8];
            accO[f] = __builtin_amdgcn_mfma_f32_16x16x32_bf16(ap0, bv0, accO[f], 0, 0, 0);
            accO[f] = __builtin_amdgcn_mfma_f32_16x16x32_bf16(ap1, bv1, accO[f], 0, 0, 0);
        }
    }

    #pragma unroll
    for (int i = 0; i < 4; ++i) {
        float inv = 1.f / Lrow[i];
        int gr = q0 + 16 * w + q * 4 + i;
        #pragma unroll
        for (int f = 0; f < 4; ++f)
            O[(size_t)gr * DMODEL + hd + f * 16 + c] = __float2bfloat16(accO[f][i] * inv);
    }
}

extern "C" void kernel_launch(void* const* d_in, const int* in_sizes, int n_in,
                              void* d_out, int out_size, void* d_ws, size_t ws_size,
                              hipStream_t stream) {
    int* flagw = (int*)d_ws;
    const int* flag = (const int*)d_ws;
    bf16* Q = (bf16*)((char*)d_ws + 256);
    bf16* K = Q + (size_t)SEQ * DMODEL;
    bf16* V = K + (size_t)SEQ * DMODEL;
    bf16* O = V + (size_t)SEQ * DMODEL;

    detect_dtype<<<1, 64, 0, stream>>>((const unsigned short*)d_in[0], flagw);

    dim3 gg(SEQ / 128, DMODEL / 128);
    dim3 blk(256);
    gemm_proj_mfma<<<gg, blk, 0, stream>>>(d_in[0], d_in[2], d_in[3], Q, flag, SEQ, DMODEL, DMODEL);
    gemm_proj_mfma<<<gg, blk, 0, stream>>>(d_in[0], d_in[4], d_in[5], K, flag, SEQ, DMODEL, DMODEL);
    gemm_proj_mfma<<<gg, blk, 0, stream>>>(d_in[0], d_in[6], d_in[7], V, flag, SEQ, DMODEL, DMODEL);

    flash_mfma<<<dim3(SEQ / 64, NHEAD), blk, 0, stream>>>(Q, K, V, d_in[1], O, flag);

    gemm_out_mfma<<<gg, blk, 0, stream>>>(O, d_in[8], d_in[9], d_out, flag, SEQ, DMODEL, DMODEL);
}

// Round 4
// 518.781 us; speedup vs baseline: 4.4049x; 1.1861x over previous
//
#include <hip/hip_runtime.h>
#include <hip/hip_bf16.h>

typedef __hip_bfloat16 bf16;
typedef __attribute__((ext_vector_type(8))) short short8;
typedef __attribute__((ext_vector_type(4))) float f32x4;

#define SEQ    4096
#define DMODEL 1024
#define NHEAD  16
#define DKH    64

#define LSTRIDE 72   // bf16 LDS row stride for 64-wide tiles (144 B, b128-aligned, 2-way banks = free)
#define KSTRIDE 72   // same for GEMM 64-wide K tiles

__device__ __forceinline__ float ldf(const float* p, size_t i) { return p[i]; }
__device__ __forceinline__ float ldf(const bf16*  p, size_t i) { return __bfloat162float(p[i]); }
__device__ __forceinline__ void stf(float* p, size_t i, float v) { p[i] = v; }
__device__ __forceinline__ void stf(bf16*  p, size_t i, float v) { p[i] = __float2bfloat16(v); }

__device__ __forceinline__ short f2bs(float v) {
    bf16 b = __float2bfloat16(v);
    return *(short*)&b;
}

__device__ __forceinline__ short8 lda8(const bf16* p, size_t i) {
    return *(const short8*)(p + i);
}
__device__ __forceinline__ short8 lda8(const float* p, size_t i) {
    float4 a = *(const float4*)(p + i);
    float4 b = *(const float4*)(p + i + 4);
    short8 r;
    r[0] = f2bs(a.x); r[1] = f2bs(a.y); r[2] = f2bs(a.z); r[3] = f2bs(a.w);
    r[4] = f2bs(b.x); r[5] = f2bs(b.y); r[6] = f2bs(b.z); r[7] = f2bs(b.w);
    return r;
}

// bf16 (flag=1) vs fp32 (flag=0) storage detector (worked in rounds 2-3).
__global__ void detect_dtype(const unsigned short* __restrict__ x, int* __restrict__ flag) {
    int lane = threadIdx.x;
    int cnt = 0;
    for (int i = lane; i < 512; i += 64) {
        int e = (x[i] >> 7) & 0xFF;
        cnt += (e >= 100 && e <= 140) ? 1 : 0;
    }
    #pragma unroll
    for (int off = 32; off; off >>= 1) cnt += __shfl_xor(cnt, off, 64);
    if (lane == 0) *flag = (cnt >= 400) ? 1 : 0;
}

// ---------------- MFMA GEMM: C[m,n] = sum_k A[m,k]*B[n,k] + bias[n] ----------------
// 128x128 tile, BK=64, 256 threads = 4 waves, each wave a 64x64 quadrant (4x4 frags).
// TRANSC: store C transposed as C[n*M + m] (bf16), packing 4 consecutive m per 8B store.
template <typename TA, typename TB, typename TC, bool TRANSC>
__device__ void gemm_mfma_body(const TA* __restrict__ A, const TB* __restrict__ B,
                               const TB* __restrict__ bias, TC* __restrict__ C,
                               int M, int N, int K, short* As, short* Bs) {
    const int tid = threadIdx.x;
    const int w = tid >> 6, lane = tid & 63, q = lane >> 4, c = lane & 15;
    const int m0 = blockIdx.x * 128, n0 = blockIdx.y * 128;
    const int mb = 64 * (w & 1), nb = 64 * (w >> 1);

    f32x4 acc[4][4] = {};

    for (int k0 = 0; k0 < K; k0 += 64) {
        __syncthreads();
        #pragma unroll
        for (int i = 0; i < 4; ++i) {
            int ch = tid + 256 * i;           // 1024 chunks of 8 elems = 128x64
            int r = ch >> 3, c8 = (ch & 7) * 8;
            *(short8*)&As[r * KSTRIDE + c8] = lda8(A, (size_t)(m0 + r) * K + k0 + c8);
            *(short8*)&Bs[r * KSTRIDE + c8] = lda8(B, (size_t)(n0 + r) * K + k0 + c8);
        }
        __syncthreads();
        #pragma unroll
        for (int kh = 0; kh < 2; ++kh) {
            const int kk = kh * 32 + q * 8;
            short8 af[4], bfr[4];
            #pragma unroll
            for (int i = 0; i < 4; ++i)
                af[i] = *(const short8*)&As[(mb + i * 16 + c) * KSTRIDE + kk];
            #pragma unroll
            for (int j = 0; j < 4; ++j)
                bfr[j] = *(const short8*)&Bs[(nb + j * 16 + c) * KSTRIDE + kk];
            #pragma unroll
            for (int i = 0; i < 4; ++i)
                #pragma unroll
                for (int j = 0; j < 4; ++j)
                    acc[i][j] = __builtin_amdgcn_mfma_f32_16x16x32_bf16(af[i], bfr[j], acc[i][j], 0, 0, 0);
        }
    }

    #pragma unroll
    for (int j = 0; j < 4; ++j) {
        int n = n0 + nb + j * 16 + c;
        float bj = ldf(bias, (size_t)n);
        #pragma unroll
        for (int i = 0; i < 4; ++i) {
            if (TRANSC) {
                short4 pk;
                pk.x = f2bs(acc[i][j][0] + bj);
                pk.y = f2bs(acc[i][j][1] + bj);
                pk.z = f2bs(acc[i][j][2] + bj);
                pk.w = f2bs(acc[i][j][3] + bj);
                int m = m0 + mb + i * 16 + q * 4;
                *(short4*)&((bf16*)C)[(size_t)n * M + m] = pk;
            } else {
                #pragma unroll
                for (int t = 0; t < 4; ++t) {
                    int m = m0 + mb + i * 16 + q * 4 + t;
                    stf(C, (size_t)m * N + n, acc[i][j][t] + bj);
                }
            }
        }
    }
}

__global__ __launch_bounds__(256)
void gemm_proj_mfma(const void* __restrict__ A, const void* __restrict__ B,
                    const void* __restrict__ bias, bf16* __restrict__ C,
                    const int* __restrict__ flag, int M, int N, int K) {
    __shared__ __align__(16) short As[128 * KSTRIDE];
    __shared__ __align__(16) short Bs[128 * KSTRIDE];
    if (*flag)
        gemm_mfma_body<bf16, bf16, bf16, false>((const bf16*)A, (const bf16*)B, (const bf16*)bias, C, M, N, K, As, Bs);
    else
        gemm_mfma_body<float, float, bf16, false>((const float*)A, (const float*)B, (const float*)bias, C, M, N, K, As, Bs);
}

// V projection with transposed output: Vt[n][m], n over DMODEL, m over SEQ.
__global__ __launch_bounds__(256)
void gemm_projT_mfma(const void* __restrict__ A, const void* __restrict__ B,
                     const void* __restrict__ bias, bf16* __restrict__ C,
                     const int* __restrict__ flag, int M, int N, int K) {
    __shared__ __align__(16) short As[128 * KSTRIDE];
    __shared__ __align__(16) short Bs[128 * KSTRIDE];
    if (*flag)
        gemm_mfma_body<bf16, bf16, bf16, true>((const bf16*)A, (const bf16*)B, (const bf16*)bias, C, M, N, K, As, Bs);
    else
        gemm_mfma_body<float, float, bf16, true>((const float*)A, (const float*)B, (const float*)bias, C, M, N, K, As, Bs);
}

__global__ __launch_bounds__(256)
void gemm_out_mfma(const bf16* __restrict__ A, const void* __restrict__ B,
                   const void* __restrict__ bias, void* __restrict__ C,
                   const int* __restrict__ flag, int M, int N, int K) {
    __shared__ __align__(16) short As[128 * KSTRIDE];
    __shared__ __align__(16) short Bs[128 * KSTRIDE];
    if (*flag)
        gemm_mfma_body<bf16, bf16, bf16, false>(A, (const bf16*)B, (const bf16*)bias, (bf16*)C, M, N, K, As, Bs);
    else
        gemm_mfma_body<bf16, float, float, false>(A, (const float*)B, (const float*)bias, (float*)C, M, N, K, As, Bs);
}

// ---------------- MFMA flash attention ----------------
// Block = 256 threads (4 waves), 64 Q rows x one head. Wave w owns rows 16w..16w+15.
// V comes pre-transposed: VtG[d_global][s], so staging is coalesced b128 like K.
// sim is read straight from global into registers (L2-served; 16 heads share each tile).
template <typename TS>
__device__ void flash_body(const bf16* __restrict__ Q, const bf16* __restrict__ Kg,
                           const bf16* __restrict__ VtG, const TS* __restrict__ sim,
                           bf16* __restrict__ O,
                           short* Qs, short* Ks, short* Vt, short* Ps) {
    const int tid = threadIdx.x;
    const int w = tid >> 6, lane = tid & 63, q = lane >> 4, c = lane & 15;
    const int q0 = blockIdx.x * 64, hd = blockIdx.y * DKH;

    // stage Q tile (unscaled; 1/8 applied post-MFMA)
    #pragma unroll
    for (int i = 0; i < 2; ++i) {
        int ch = tid + 256 * i;
        int r = ch >> 3, c8 = (ch & 7) * 8;
        *(short8*)&Qs[r * LSTRIDE + c8] = *(const short8*)&Q[(size_t)(q0 + r) * DMODEL + hd + c8];
    }

    f32x4 accO[4] = {};
    float Mrow[4], Lrow[4];
    #pragma unroll
    for (int i = 0; i < 4; ++i) { Mrow[i] = -1e30f; Lrow[i] = 0.f; }

    for (int t = 0; t < SEQ / 64; ++t) {
        const int k0 = t * 64;
        __syncthreads();  // prior iter's Ks/Vt reads complete (covers Qs at t=0)

        #pragma unroll
        for (int i = 0; i < 2; ++i) {
            int ch = tid + 256 * i;
            int r = ch >> 3, c8 = (ch & 7) * 8;
            *(short8*)&Ks[r * LSTRIDE + c8] = *(const short8*)&Kg[(size_t)(k0 + r) * DMODEL + hd + c8];
            *(short8*)&Vt[r * LSTRIDE + c8] = *(const short8*)&VtG[(size_t)(hd + r) * SEQ + k0 + c8];
        }
        __syncthreads();

        // sim tile -> registers (independent of LDS; overlaps with MFMA issue)
        float sm[4][4];
        #pragma unroll
        for (int f = 0; f < 4; ++f)
            #pragma unroll
            for (int i = 0; i < 4; ++i)
                sm[f][i] = ldf(sim, (size_t)(q0 + 16 * w + q * 4 + i) * SEQ + k0 + f * 16 + c);

        // QK^T: S strip rows 16w..16w+15, cols 0..63
        short8 aq0 = *(const short8*)&Qs[(16 * w + c) * LSTRIDE + q * 8];
        short8 aq1 = *(const short8*)&Qs[(16 * w + c) * LSTRIDE + 32 + q * 8];
        f32x4 sfr[4];
        #pragma unroll
        for (int f = 0; f < 4; ++f) {
            short8 bk0 = *(const short8*)&Ks[(f * 16 + c) * LSTRIDE + q * 8];
            short8 bk1 = *(const short8*)&Ks[(f * 16 + c) * LSTRIDE + 32 + q * 8];
            f32x4 a = {};
            a = __builtin_amdgcn_mfma_f32_16x16x32_bf16(aq0, bk0, a, 0, 0, 0);
            a = __builtin_amdgcn_mfma_f32_16x16x32_bf16(aq1, bk1, a, 0, 0, 0);
            sfr[f] = a;
        }

        // softmax (row r = 16w + q*4 + i lives in the 16 lanes of quad q)
        float sv[4][4], rmax[4];
        #pragma unroll
        for (int i = 0; i < 4; ++i) rmax[i] = -1e30f;
        #pragma unroll
        for (int f = 0; f < 4; ++f)
            #pragma unroll
            for (int i = 0; i < 4; ++i) {
                float s = sfr[f][i] * 0.125f + sm[f][i];
                sv[f][i] = s;
                rmax[i] = fmaxf(rmax[i], s);
            }
        #pragma unroll
        for (int off = 1; off < 16; off <<= 1)
            #pragma unroll
            for (int i = 0; i < 4; ++i)
                rmax[i] = fmaxf(rmax[i], __shfl_xor(rmax[i], off, 64));

        float alpha[4], rsum[4];
        #pragma unroll
        for (int i = 0; i < 4; ++i) {
            float mn = fmaxf(Mrow[i], rmax[i]);
            alpha[i] = __expf(Mrow[i] - mn);
            Mrow[i] = mn;
            rsum[i] = 0.f;
        }
        #pragma unroll
        for (int f = 0; f < 4; ++f)
            #pragma unroll
            for (int i = 0; i < 4; ++i) {
                float p = __expf(sv[f][i] - Mrow[i]);
                sv[f][i] = p;
                rsum[i] += p;
            }
        #pragma unroll
        for (int off = 1; off < 16; off <<= 1)
            #pragma unroll
            for (int i = 0; i < 4; ++i)
                rsum[i] += __shfl_xor(rsum[i], off, 64);
        #pragma unroll
        for (int i = 0; i < 4; ++i)
            Lrow[i] = Lrow[i] * alpha[i] + rsum[i];

        // P (bf16) -> A-operand layout via LDS. Wave-local rows: no __syncthreads needed.
        #pragma unroll
        for (int f = 0; f < 4; ++f)
            #pragma unroll
            for (int i = 0; i < 4; ++i)
                Ps[(16 * w + q * 4 + i) * LSTRIDE + f * 16 + c] = f2bs(sv[f][i]);

        #pragma unroll
        for (int f = 0; f < 4; ++f)
            #pragma unroll
            for (int i = 0; i < 4; ++i)
                accO[f][i] *= alpha[i];

        // PV: O[m][d] += sum_n P[m][n] * Vt[d][n]
        short8 ap0 = *(const short8*)&Ps[(16 * w + c) * LSTRIDE + q * 8];
        short8 ap1 = *(const short8*)&Ps[(16 * w + c) * LSTRIDE + 32 + q * 8];
        #pragma unroll
        for (int f = 0; f < 4; ++f) {
            short8 bv0 = *(const short8*)&Vt[(f * 16 + c) * LSTRIDE + q * 8];
            short8 bv1 = *(const short8*)&Vt[(f * 16 + c) * LSTRIDE + 32 + q * 8];
            accO[f] = __builtin_amdgcn_mfma_f32_16x16x32_bf16(ap0, bv0, accO[f], 0, 0, 0);
            accO[f] = __builtin_amdgcn_mfma_f32_16x16x32_bf16(ap1, bv1, accO[f], 0, 0, 0);
        }
    }

    #pragma unroll
    for (int i = 0; i < 4; ++i) {
        float inv = 1.f / Lrow[i];
        int gr = q0 + 16 * w + q * 4 + i;
        #pragma unroll
        for (int f = 0; f < 4; ++f)
            O[(size_t)gr * DMODEL + hd + f * 16 + c] = __float2bfloat16(accO[f][i] * inv);
    }
}

__global__ __launch_bounds__(256)
void flash_mfma(const bf16* __restrict__ Q, const bf16* __restrict__ K,
                const bf16* __restrict__ Vt, const void* __restrict__ sim,
                bf16* __restrict__ O, const int* __restrict__ flag) {
    __shared__ __align__(16) short Qs[64 * LSTRIDE];
    __shared__ __align__(16) short Ks[64 * LSTRIDE];
    __shared__ __align__(16) short Vs[64 * LSTRIDE];
    __shared__ __align__(16) short Ps[64 * LSTRIDE];
    if (*flag)
        flash_body<bf16>(Q, K, Vt, (const bf16*)sim, O, Qs, Ks, Vs, Ps);
    else
        flash_body<float>(Q, K, Vt, (const float*)sim, O, Qs, Ks, Vs, Ps);
}

extern "C" void kernel_launch(void* const* d_in, const int* in_sizes, int n_in,
                              void* d_out, int out_size, void* d_ws, size_t ws_size,
                              hipStream_t stream) {
    int* flagw = (int*)d_ws;
    const int* flag = (const int*)d_ws;
    bf16* Q  = (bf16*)((char*)d_ws + 256);
    bf16* K  = Q + (size_t)SEQ * DMODEL;
    bf16* Vt = K + (size_t)SEQ * DMODEL;   // transposed: [DMODEL][SEQ]
    bf16* O  = Vt + (size_t)SEQ * DMODEL;

    detect_dtype<<<1, 64, 0, stream>>>((const unsigned short*)d_in[0], flagw);

    dim3 gg(SEQ / 128, DMODEL / 128);
    dim3 blk(256);
    gemm_proj_mfma <<<gg, blk, 0, stream>>>(d_in[0], d_in[2], d_in[3], Q,  flag, SEQ, DMODEL, DMODEL);
    gemm_proj_mfma <<<gg, blk, 0, stream>>>(d_in[0], d_in[4], d_in[5], K,  flag, SEQ, DMODEL, DMODEL);
    gemm_projT_mfma<<<gg, blk, 0, stream>>>(d_in[0], d_in[6], d_in[7], Vt, flag, SEQ, DMODEL, DMODEL);

    flash_mfma<<<dim3(SEQ / 64, NHEAD), blk, 0, stream>>>(Q, K, Vt, d_in[1], O, flag);

    gemm_out_mfma<<<gg, blk, 0, stream>>>(O, d_in[8], d_in[9], d_out, flag, SEQ, DMODEL, DMODEL);
}